// Round 1
// baseline (458.584 us; speedup 1.0000x reference)
//
#include <hip/hip_runtime.h>
#include <stdint.h>

// out = relu(A) * mask(top-64 per row), A: 8192x8192 fp32. Exact (bit-exact
// threshold + lowest-index-first tie handling, matching lax.top_k + scatter).
//
// One block per row; values stay in registers (32/thread).
//  1) row max fused into load; exponent-window counts via per-thread bitmasks
//  2) K-th element's EXPONENT resolved algebraically from window counts
//     (no radix pass over the top byte) -> compact only the threshold binade
//  3) mantissa radix (<=3 byte passes) with fused 4-copy scan + ping-pong
//     hists (2 barriers/pass) and early-exit find-scan when bin count == 1
//  4) write relu(A) masked by threshold; exact tie fixup
// Cold-path fallbacks (never taken for normal data) keep it exact for any input.

typedef float f32x4 __attribute__((ext_vector_type(4)));

constexpr int N      = 8192;
constexpr int K      = 64;
constexpr int BLOCK  = 256;
constexpr int VPT    = N / BLOCK;   // 32 values/thread in registers
constexpr int V4     = VPT / 4;     // 8 float4 per thread
constexpr int CAP    = 1536;        // candidate list capacity
constexpr int EQ_CAP = 256;

__device__ __forceinline__ uint32_t wave_reduce_add(uint32_t x) {
    #pragma unroll
    for (int d = 32; d >= 1; d >>= 1) x += __shfl_down(x, d, 64);
    return x;   // valid in lane 0
}

// wave 0 only: pick digit at `shift`, summing the 4 per-wave hist copies
// inline (no block-wide sum step). Also exports the chosen bin's count.
__device__ __forceinline__ void scan_pick2(const uint32_t (*h)[256],
                                           uint32_t* s_prefix, uint32_t* s_k,
                                           uint32_t* s_hb, int shift, int lane) {
    uint32_t k  = *s_k;
    uint32_t h0 = h[0][4*lane+0] + h[1][4*lane+0] + h[2][4*lane+0] + h[3][4*lane+0];
    uint32_t h1 = h[0][4*lane+1] + h[1][4*lane+1] + h[2][4*lane+1] + h[3][4*lane+1];
    uint32_t h2 = h[0][4*lane+2] + h[1][4*lane+2] + h[2][4*lane+2] + h[3][4*lane+2];
    uint32_t h3 = h[0][4*lane+3] + h[1][4*lane+3] + h[2][4*lane+3] + h[3][4*lane+3];
    uint32_t suf = h0 + h1 + h2 + h3;
    #pragma unroll
    for (int d = 1; d < 64; d <<= 1) {          // suffix sum across lanes
        uint32_t o = __shfl_down(suf, d, 64);
        if (lane + d < 64) suf += o;
    }
    unsigned long long m = __ballot(suf >= k);  // nonzero by invariant
    int cl = 63 - __builtin_clzll(m);
    if (lane == cl) {
        uint32_t S0 = suf, S1 = S0 - h0, S2 = S1 - h1, S3 = S2 - h2;
        int b; uint32_t Sb, hb;
        if      (S3 >= k) { b = 3; Sb = S3; hb = h3; }
        else if (S2 >= k) { b = 2; Sb = S2; hb = h2; }
        else if (S1 >= k) { b = 1; Sb = S1; hb = h1; }
        else              { b = 0; Sb = S0; hb = h0; }
        *s_prefix |= (uint32_t)(4*lane + b) << shift;
        *s_k  = k - (Sb - hb);                  // strictly-greater removed
        *s_hb = hb;
    }
}

__global__ __launch_bounds__(BLOCK) void topk_row_kernel(
    const float* __restrict__ A, float* __restrict__ out)
{
    __shared__ uint32_t hist[2][4][256];  // ping-pong x per-wave copies
    __shared__ uint32_t list[CAP];        // candidate bit patterns
    __shared__ uint32_t s_eq[EQ_CAP];     // indices of elements == T
    __shared__ uint32_t s_rb[4][3];       // cross-wave reduce scratch (packed)
    __shared__ uint32_t s_rmax[4];
    __shared__ uint32_t s_prefix, s_k, s_hb, s_T, s_cnt, s_listcnt, s_min;

    const int tid  = threadIdx.x;
    const int wave = tid >> 6;
    const int lane = tid & 63;
    const int row  = blockIdx.x;

    const float4* rowp = reinterpret_cast<const float4*>(A + (size_t)row * N);
    float4*       outp = reinterpret_cast<float4*>(out + (size_t)row * N);

    // ---- load + relu into registers; row max fused into the load loop ----
    uint32_t v[VPT];
    uint32_t mx = 0;
    #pragma unroll
    for (int j = 0; j < V4; ++j) {
        float4 f = rowp[tid + j * BLOCK];
        uint32_t x0 = (f.x > 0.f) ? __float_as_uint(f.x) : 0u;
        uint32_t x1 = (f.y > 0.f) ? __float_as_uint(f.y) : 0u;
        uint32_t x2 = (f.z > 0.f) ? __float_as_uint(f.z) : 0u;
        uint32_t x3 = (f.w > 0.f) ? __float_as_uint(f.w) : 0u;
        v[4*j+0] = x0; v[4*j+1] = x1; v[4*j+2] = x2; v[4*j+3] = x3;
        uint32_t m01 = x0 > x1 ? x0 : x1;
        uint32_t m23 = x2 > x3 ? x2 : x3;
        uint32_t mm  = m01 > m23 ? m01 : m23;
        mx = mm > mx ? mm : mx;
    }
    #pragma unroll
    for (int d = 32; d >= 1; d >>= 1) {
        uint32_t o = __shfl_down(mx, d, 64);
        mx = o > mx ? o : mx;
    }
    if (lane == 0) s_rmax[wave] = mx;
    if (tid == 0) { s_listcnt = 0; s_cnt = 0; }
    __syncthreads();                                          // [A]
    // every thread computes expM itself (no tid0 round-trip barrier)
    uint32_t ma = s_rmax[0], mb = s_rmax[1], mc = s_rmax[2], md = s_rmax[3];
    ma = mb > ma ? mb : ma; mc = md > mc ? md : mc;
    const uint32_t expM = (mc > ma ? mc : ma) >> 23;

    // ---- 4-binade window via per-thread bitmasks (reused for compaction) ----
    uint32_t cm0 = 0, cm1 = 0, cm2 = 0, cm3 = 0, mnz = 0;
    #pragma unroll
    for (int j = 0; j < VPT; ++j) {
        uint32_t x = v[j];
        if (x != 0u) {
            uint32_t d   = expM - (x >> 23);
            uint32_t bit = 1u << j;
            mnz |= bit;
            if      (d == 0u) cm0 |= bit;
            else if (d == 1u) cm1 |= bit;
            else if (d == 2u) cm2 |= bit;
            else if (d == 3u) cm3 |= bit;
        }
    }
    // packed reduces: halves never exceed 64*32=2048, no carry between halves
    uint32_t r01 = (uint32_t)__popc(cm0) | ((uint32_t)__popc(cm1) << 16);
    uint32_t r23 = (uint32_t)__popc(cm2) | ((uint32_t)__popc(cm3) << 16);
    uint32_t rcp = (uint32_t)__popc(mnz);
    r01 = wave_reduce_add(r01);
    r23 = wave_reduce_add(r23);
    rcp = wave_reduce_add(rcp);
    if (lane == 0) { s_rb[wave][0] = r01; s_rb[wave][1] = r23; s_rb[wave][2] = rcp; }
    __syncthreads();                                          // [B]
    uint32_t t01  = s_rb[0][0] + s_rb[1][0] + s_rb[2][0] + s_rb[3][0];
    uint32_t t23  = s_rb[0][1] + s_rb[1][1] + s_rb[2][1] + s_rb[3][1];
    uint32_t cpos = s_rb[0][2] + s_rb[1][2] + s_rb[2][2] + s_rb[3][2];
    uint32_t B0 = t01 & 0xFFFFu, B1 = t01 >> 16;
    uint32_t B2 = t23 & 0xFFFFu, B3 = t23 >> 16;

    if (cpos < (uint32_t)K) {                 // < K positives: out = relu(A)
        #pragma unroll
        for (int j = 0; j < V4; ++j) {
            float4 o;
            o.x = __uint_as_float(v[4*j+0]); o.y = __uint_as_float(v[4*j+1]);
            o.z = __uint_as_float(v[4*j+2]); o.w = __uint_as_float(v[4*j+3]);
            __builtin_nontemporal_store(*(const f32x4*)&o,
                                        (f32x4*)&outp[tid + j * BLOCK]);
        }
        return;
    }

    // ---- resolve the K-th element's exponent without a radix pass ----
    uint32_t cum1 = B0 + B1, cum2 = cum1 + B2, cum3 = cum2 + B3;
    const bool windowOK = (cum3 >= (uint32_t)K);
    uint32_t C, kk, hbInit, prefixInit, ecut, sel = 0;
    bool needExp;
    if (windowOK) {
        uint32_t jf, cumBefore;
        if      (B0   >= (uint32_t)K) { jf = 0; cumBefore = 0;    C = B0; sel = cm0; }
        else if (cum1 >= (uint32_t)K) { jf = 1; cumBefore = B0;   C = B1; sel = cm1; }
        else if (cum2 >= (uint32_t)K) { jf = 2; cumBefore = cum1; C = B2; sel = cm2; }
        else                          { jf = 3; cumBefore = cum2; C = B3; sel = cm3; }
        ecut       = expM - jf;           // exponent of the K-th element
        kk         = (uint32_t)K - cumBefore;
        hbInit     = C;                   // elements in the threshold binade
        prefixInit = ecut << 23;          // top 9 bits of T already known
        needExp    = false;
    } else {
        // cold: widen exponent window until >= K candidates
        ecut = (expM > 7u) ? (expM - 7u) : 0u;
        for (;;) {
            uint32_t lc = 0;
            #pragma unroll
            for (int j = 0; j < VPT; ++j) {
                uint32_t x = v[j];
                lc += (x != 0u && (x >> 23) >= ecut) ? 1u : 0u;
            }
            lc = wave_reduce_add(lc);
            __syncthreads();              // WAR guard on s_rb
            if (lane == 0) s_rb[wave][0] = lc;
            __syncthreads();
            C = s_rb[0][0] + s_rb[1][0] + s_rb[2][0] + s_rb[3][0];
            if (C >= (uint32_t)K || ecut == 0u) break;
            ecut = (ecut > 4u) ? (ecut - 4u) : 0u;
        }
        kk = (uint32_t)K; hbInit = 0xFFFFFFFFu; prefixInit = 0u;
        needExp = true;                   // exponent pass still required
    }
    if (tid == 0) { s_prefix = prefixInit; s_k = kk; s_hb = hbInit; }

    // ---- shared radix engine: mantissa passes w/ ping-pong hists,
    //      fused pick, and early-exit find-scan when chosen bin == 1 ----
    int resShift = 23;                    // bits >= resShift resolved
    uint32_t T = 0, need = 1;
    auto radix = [&](auto&& forEach, bool needE) {
        int buf = 0;
        if (needE) {                      // exponent byte pass (cold paths)
            forEach([&](uint32_t x) { atomicAdd(&hist[0][wave][x >> 23], 1u); });
            __syncthreads();
            if (wave == 0) scan_pick2(hist[0], &s_prefix, &s_k, &s_hb, 23, lane);
            __syncthreads();
            buf = 1;
        }
        for (int shift = 16; shift >= 0; shift -= 8) {
            if (s_hb == 1u) break;        // uniform: read post-barrier
            const uint32_t prefix = s_prefix;
            const uint32_t himask = ~0u << resShift;
            #pragma unroll                // clear next buffer while using cur
            for (int b = lane; b < 256; b += 64) hist[buf ^ 1][wave][b] = 0;
            forEach([&](uint32_t x) {
                if ((x & himask) == prefix)
                    atomicAdd(&hist[buf][wave][(x >> shift) & 255u], 1u);
            });
            __syncthreads();
            if (wave == 0) scan_pick2(hist[buf], &s_prefix, &s_k, &s_hb, shift, lane);
            __syncthreads();
            buf ^= 1;
            resShift = shift;
        }
        if (s_hb == 1u && resShift > 0) { // unique survivor: one scan finds T
            const uint32_t mlo = ~0u << resShift;
            const uint32_t pfx = s_prefix;
            forEach([&](uint32_t x) { if ((x & mlo) == pfx) s_T = x; });
            __syncthreads();
            T = s_T;
        } else {
            T = s_prefix;
        }
        need = s_k;                       // #elements == T inside top-K
    };

    if (C <= (uint32_t)CAP) {
        // ---- hot: compact threshold-binade candidates into LDS list ----
        uint32_t lsel;
        if (windowOK) {
            lsel = sel;                   // mask already built (zero-free)
        } else {
            lsel = 0;
            #pragma unroll
            for (int j = 0; j < VPT; ++j) {
                uint32_t x = v[j];
                if (x != 0u && (x >> 23) >= ecut) lsel |= 1u << j;
            }
        }
        uint32_t lc   = (uint32_t)__popc(lsel);
        uint32_t incl = lc;
        #pragma unroll
        for (int d = 1; d < 64; d <<= 1) {
            uint32_t t = __shfl_up(incl, d, 64);
            if (lane >= d) incl += t;
        }
        uint32_t baseV = 0;
        if (lane == 63) baseV = atomicAdd(&s_listcnt, incl);  // 1 atomic/wave
        uint32_t base = __shfl(baseV, 63, 64);
        uint32_t pos  = base + (incl - lc);
        #pragma unroll
        for (int j = 0; j < VPT; ++j)
            if (lsel & (1u << j)) list[pos++] = v[j];
        #pragma unroll
        for (int b = lane; b < 256; b += 64) { hist[0][wave][b] = 0; hist[1][wave][b] = 0; }
        __syncthreads();                                      // [C]

        auto forEachList = [&](auto&& f) {
            for (uint32_t i = tid; i < C; i += BLOCK) f(list[i]);
        };
        radix(forEachList, needExp);
    } else {
        // ---- cold: radix straight over registers (rare, exact) ----
        #pragma unroll
        for (int b = lane; b < 256; b += 64) { hist[0][wave][b] = 0; hist[1][wave][b] = 0; }
        __syncthreads();

        auto forEachReg = [&](auto&& f) {
            #pragma unroll
            for (int j = 0; j < VPT; ++j) if (v[j] != 0u) f(v[j]);
        };
        radix(forEachReg, needExp);
    }

    // ---- output: keep x > T; among x == T keep `need` lowest indices ----
    const float Tf = __uint_as_float(T);
    #pragma unroll
    for (int j = 0; j < V4; ++j) {
        const int base = (tid + j * BLOCK) * 4;
        float4 o;
        float* oc = &o.x;
        #pragma unroll
        for (int c = 0; c < 4; ++c) {
            uint32_t x = v[4*j+c];
            float val = 0.f;
            if (x > T) {
                val = __uint_as_float(x);
            } else if (x == T) {
                uint32_t p = atomicAdd(&s_cnt, 1u);
                if (p < (uint32_t)EQ_CAP) s_eq[p] = (uint32_t)(base + c);
            }
            oc[c] = val;
        }
        __builtin_nontemporal_store(*(const f32x4*)&o,
                                    (f32x4*)&outp[tid + j * BLOCK]);
    }
    __syncthreads();

    const uint32_t cnt = s_cnt;
    if (cnt <= (uint32_t)EQ_CAP) {
        if (tid == 0) {
            for (uint32_t n = 0; n < need; ++n) {      // need is typically 1
                uint32_t best = 0xFFFFFFFFu, bi = 0;
                for (uint32_t i = 0; i < cnt; ++i)
                    if (s_eq[i] < best) { best = s_eq[i]; bi = i; }
                if (best != 0xFFFFFFFFu) {
                    s_eq[bi] = 0xFFFFFFFFu;
                    out[(size_t)row * N + best] = Tf;
                }
            }
        }
    } else {
        // cold exact fallback (> EQ_CAP ties): successive minima via atomicMin
        uint32_t last = 0;
        for (uint32_t n = 0; n < need; ++n) {
            __syncthreads();              // WAR guard on s_min
            if (tid == 0) s_min = 0xFFFFFFFFu;
            __syncthreads();
            #pragma unroll
            for (int j = 0; j < VPT; ++j) {
                if (v[j] == T) {
                    uint32_t g = (uint32_t)(tid + (j >> 2) * BLOCK) * 4u
                               + (uint32_t)(j & 3);
                    if (n == 0 || g > last) atomicMin(&s_min, g);
                }
            }
            __syncthreads();
            last = s_min;
            if (tid == 0 && last != 0xFFFFFFFFu) out[(size_t)row * N + last] = Tf;
        }
    }
}

extern "C" void kernel_launch(void* const* d_in, const int* in_sizes, int n_in,
                              void* d_out, int out_size, void* d_ws, size_t ws_size,
                              hipStream_t stream) {
    const float* A = (const float*)d_in[0];   // 8192*8192 fp32
    // d_in[1] (idx) is unused by the reference.
    float* out = (float*)d_out;
    topk_row_kernel<<<N, BLOCK, 0, stream>>>(A, out);
}

// Round 2
// 456.400 us; speedup vs baseline: 1.0048x; 1.0048x over previous
//
#include <hip/hip_runtime.h>
#include <stdint.h>

// out = relu(A) * mask(top-64 per row), A: 8192x8192 fp32. Exact (bit-exact
// threshold + lowest-index-first tie handling, matching lax.top_k + scatter).
//
// ONE ROW PER WAVE (64 lanes x 128 values in registers). No __syncthreads
// anywhere: all reductions are shuffles, histograms are wave-private LDS
// (DS ops from one wave execute in order). This removes the vmcnt(0) drains
// that barrier-synced 256-thread blocks paid at every phase boundary and
// lets resident waves destagger to keep HBM busy.
//
//  1) load+relu+max fused (32 independent dwordx4 loads -> deep MLP)
//  2) K-th element's EXPONENT resolved algebraically from 4-binade counts
//  3) mantissa radix over the threshold binade only (LDS list, ~100 elems),
//     with early exit when chosen bin count==1 (unique -> find-scan) or
//     bin count==k (all in top-K -> min-scan). Typically 1 histogram pass.
//  4) write relu(A) masked by threshold (keep x>=T when #ties==slots, the
//     common case); rare tie-selection path kept exact via global re-scan.
// Cold paths (huge binade, >K-way ties) re-read the row from global (L2-hot)
// with compact rolled loops - exact for any input, tiny code.

constexpr int N     = 8192;
constexpr int K     = 64;
constexpr int BLOCK = 256;      // 4 independent waves per block
constexpr int RPB   = 4;        // rows per block (= waves per block)
constexpr int VPT   = N / 64;   // 128 values per lane
constexpr int V4    = VPT / 4;  // 32 float4 per lane
constexpr int CAP   = 1536;     // per-wave candidate list capacity

__device__ __forceinline__ uint32_t bf_max(uint32_t x) {
    #pragma unroll
    for (int d = 32; d >= 1; d >>= 1) {
        uint32_t o = (uint32_t)__shfl_xor((int)x, d, 64);
        x = o > x ? o : x;
    }
    return x;   // all lanes hold the max
}
__device__ __forceinline__ uint32_t bf_add(uint32_t x) {
    #pragma unroll
    for (int d = 32; d >= 1; d >>= 1) x += (uint32_t)__shfl_xor((int)x, d, 64);
    return x;   // all lanes hold the sum
}
__device__ __forceinline__ uint32_t bf_min(uint32_t x) {
    #pragma unroll
    for (int d = 32; d >= 1; d >>= 1) {
        uint32_t o = (uint32_t)__shfl_xor((int)x, d, 64);
        x = o < x ? o : x;
    }
    return x;   // all lanes hold the min
}

// One radix digit selection over a wave-private 256-bin LDS histogram.
// prefix/k/hb are wave-uniform registers; digit is 8 bits at `shift`.
__device__ __forceinline__ void pick_digit(const uint32_t* __restrict__ h,
                                           int lane, int shift,
                                           uint32_t& prefix, uint32_t& k,
                                           uint32_t& hb) {
    uint4 hv = *reinterpret_cast<const uint4*>(&h[4 * lane]);  // ds_read_b128
    uint32_t h0 = hv.x, h1 = hv.y, h2 = hv.z, h3 = hv.w;
    uint32_t suf = h0 + h1 + h2 + h3;
    #pragma unroll
    for (int d = 1; d < 64; d <<= 1) {          // suffix sum across lanes
        uint32_t o = (uint32_t)__shfl_down((int)suf, d, 64);
        suf += (lane + d < 64) ? o : 0u;
    }
    unsigned long long m = __ballot(suf >= k);  // nonzero by invariant
    int cl = 63 - __builtin_clzll(m);           // highest lane with suffix>=k
    uint32_t S0 = suf, S1 = S0 - h0, S2 = S1 - h1, S3 = S2 - h2;
    int b; uint32_t Sb, hbl;
    if      (S3 >= k) { b = 3; Sb = S3; hbl = h3; }
    else if (S2 >= k) { b = 2; Sb = S2; hbl = h2; }
    else if (S1 >= k) { b = 1; Sb = S1; hbl = h1; }
    else              { b = 0; Sb = S0; hbl = h0; }
    uint32_t dig  = (uint32_t)(4 * lane + b);
    uint32_t knew = k - (Sb - hbl);
    dig  = (uint32_t)__shfl((int)dig,  cl, 64);
    knew = (uint32_t)__shfl((int)knew, cl, 64);
    hb   = (uint32_t)__shfl((int)hbl,  cl, 64);
    prefix |= dig << shift;
    k = knew;
}

__global__ __launch_bounds__(BLOCK, 2) void topk_row_kernel(
    const float* __restrict__ A, float* __restrict__ out)
{
    __shared__ __align__(16) uint32_t lds_list[RPB][CAP];
    __shared__ __align__(16) uint32_t lds_hist[RPB][2][256];

    const int tid  = threadIdx.x;
    const int wv   = tid >> 6;
    const int lane = tid & 63;
    const int row  = blockIdx.x * RPB + wv;

    uint32_t (&list)[CAP]    = lds_list[wv];
    uint32_t (&hist)[2][256] = lds_hist[wv];

    const float*  rp  = A + (size_t)row * N;
    const float4* rp4 = reinterpret_cast<const float4*>(rp);
    float4*       op4 = reinterpret_cast<float4*>(out + (size_t)row * N);

    // ---- load + relu into registers; fused row max (uint order == float) ----
    uint32_t v[VPT];
    uint32_t mx = 0;
    #pragma unroll
    for (int i = 0; i < V4; ++i) {
        float4 f = rp4[lane + i * 64];
        uint32_t x0 = (f.x > 0.f) ? __float_as_uint(f.x) : 0u;
        uint32_t x1 = (f.y > 0.f) ? __float_as_uint(f.y) : 0u;
        uint32_t x2 = (f.z > 0.f) ? __float_as_uint(f.z) : 0u;
        uint32_t x3 = (f.w > 0.f) ? __float_as_uint(f.w) : 0u;
        v[4*i+0] = x0; v[4*i+1] = x1; v[4*i+2] = x2; v[4*i+3] = x3;
        uint32_t a = x0 > x1 ? x0 : x1;
        uint32_t b = x2 > x3 ? x2 : x3;
        uint32_t c = a > b ? a : b;
        mx = c > mx ? c : mx;
    }
    mx = bf_max(mx);
    const uint32_t expM = mx >> 23;

    // ---- 4-binade window counts (per-thread, then packed wave reduce) ----
    uint32_t b0 = 0, b1 = 0, b2 = 0, b3 = 0, cp = 0;
    #pragma unroll
    for (int j = 0; j < VPT; ++j) {
        uint32_t x = v[j];
        if (x != 0u) {
            uint32_t d = expM - (x >> 23);
            cp += 1u;
            b0 += (d == 0u); b1 += (d == 1u); b2 += (d == 2u); b3 += (d == 3u);
        }
    }
    // halves sum to <= 8192 < 2^16: no carry between packed halves
    uint32_t r01  = bf_add(b0 | (b1 << 16));
    uint32_t r23  = bf_add(b2 | (b3 << 16));
    uint32_t cpos = bf_add(cp);
    uint32_t B0 = r01 & 0xFFFFu, B1 = r01 >> 16;
    uint32_t B2 = r23 & 0xFFFFu, B3 = r23 >> 16;

    uint32_t T = 1u;        // default: keep all positives (x>=1 <=> x>0)
    bool keepAll = true;
    uint32_t needOut = 0;

    if (cpos >= (uint32_t)K) {
        uint32_t cum1 = B0 + B1, cum2 = cum1 + B2, cum3 = cum2 + B3;
        const bool windowOK = (cum3 >= (uint32_t)K);

        uint32_t prefix, k, hb, elow, ehigh, C, lc = 0;
        int resShift;
        bool needExp;
        if (windowOK) {
            uint32_t cumBefore;
            uint32_t jf;
            if      (B0   >= (uint32_t)K) { jf = 0; cumBefore = 0;    C = B0; lc = b0; }
            else if (cum1 >= (uint32_t)K) { jf = 1; cumBefore = B0;   C = B1; lc = b1; }
            else if (cum2 >= (uint32_t)K) { jf = 2; cumBefore = cum1; C = B2; lc = b2; }
            else                          { jf = 3; cumBefore = cum2; C = B3; lc = b3; }
            uint32_t ecut = expM - jf;    // exponent of the K-th element
            k        = (uint32_t)K - cumBefore;
            hb       = C;
            prefix   = ecut << 23;        // top 9 bits of T already known
            resShift = 23;
            needExp  = false;
            elow = ehigh = ecut;
        } else {
            // cold: radix over ALL positives, exponent pass included
            k = (uint32_t)K; hb = cpos; prefix = 0u; resShift = 32;
            needExp = true; elow = 0u; ehigh = 255u; C = 0xFFFFFFFFu;
        }

        // ---- wave-local radix engine over a candidate stream ----
        auto radix = [&](auto&& forEach) {
            int buf = 0;
            for (int s = needExp ? 23 : 16; s >= 0; s = (s == 23) ? 16 : (s - 8)) {
                if (hb == 1u || hb == k) break;   // early-resolvable
                uint4 z; z.x = 0u; z.y = 0u; z.z = 0u; z.w = 0u;
                *reinterpret_cast<uint4*>(&hist[buf][4 * lane]) = z;
                __asm__ volatile("" ::: "memory");
                const uint32_t himask = (resShift >= 32) ? 0u : (~0u << resShift);
                const uint32_t pfx = prefix;
                forEach([&](uint32_t x) {
                    if ((x & himask) == pfx)
                        atomicAdd(&hist[buf][(x >> s) & 255u], 1u);
                });
                __asm__ volatile("" ::: "memory");
                pick_digit(hist[buf], lane, s, prefix, k, hb);
                resShift = (s == 23) ? 23 : s;
                buf ^= 1;
            }
            if (hb == 1u && resShift > 0) {
                // unique survivor: one scan finds T; exactly one element == T
                const uint32_t himask = (resShift >= 32) ? 0u : (~0u << resShift);
                const uint32_t pfx = prefix;
                uint32_t fx = 0u, fnd = 0u;
                forEach([&](uint32_t x) {
                    if ((x & himask) == pfx) { fx = x; fnd = 1u; }
                });
                unsigned long long m = __ballot(fnd != 0u);
                int src = __builtin_ctzll(m);
                T = (uint32_t)__shfl((int)fx, src, 64);
                keepAll = true;           // cnt_eq == 1 == k
            } else if (hb == k && resShift > 0) {
                // all prefix-matching elements are top-K: T = their min
                const uint32_t himask = (resShift >= 32) ? 0u : (~0u << resShift);
                const uint32_t pfx = prefix;
                uint32_t mn = 0xFFFFFFFFu;
                forEach([&](uint32_t x) {
                    if ((x & himask) == pfx) mn = x < mn ? x : mn;
                });
                T = bf_min(mn);
                keepAll = true;           // need == cnt_eq
            } else {
                T = prefix;               // fully resolved
                keepAll = (k == hb);      // ties all kept?
                needOut = k;
            }
        };

        if (windowOK && C <= (uint32_t)CAP) {
            // ---- hot: compact threshold-binade candidates into LDS list ----
            uint32_t incl = lc;
            #pragma unroll
            for (int d = 1; d < 64; d <<= 1) {
                uint32_t t = (uint32_t)__shfl_up((int)incl, d, 64);
                if (lane >= d) incl += t;
            }
            uint32_t pos = incl - lc;     // exclusive prefix
            const uint32_t ecut = elow;
            #pragma unroll
            for (int j = 0; j < VPT; ++j) {
                uint32_t x = v[j];
                if (x != 0u && (x >> 23) == ecut) list[pos++] = x;
            }
            __asm__ volatile("" ::: "memory");
            const uint32_t Cc = C;
            radix([&](auto&& f) {
                for (uint32_t i = (uint32_t)lane; i < Cc; i += 64u) f(list[i]);
            });
        } else {
            // ---- cold: stream candidates from global (L2-hot row re-read) ----
            const uint32_t el = elow, eh = ehigh;
            radix([&](auto&& f) {
                for (int i = lane; i < N; i += 64) {
                    float fv = rp[i];
                    uint32_t x = (fv > 0.f) ? __float_as_uint(fv) : 0u;
                    if (x != 0u) {
                        uint32_t e = x >> 23;
                        if (e >= el && e <= eh) f(x);
                    }
                }
            });
        }
    }

    // ---- output ----
    if (keepAll) {
        #pragma unroll
        for (int i = 0; i < V4; ++i) {
            float4 o;
            o.x = (v[4*i+0] >= T) ? __uint_as_float(v[4*i+0]) : 0.f;
            o.y = (v[4*i+1] >= T) ? __uint_as_float(v[4*i+1]) : 0.f;
            o.z = (v[4*i+2] >= T) ? __uint_as_float(v[4*i+2]) : 0.f;
            o.w = (v[4*i+3] >= T) ? __uint_as_float(v[4*i+3]) : 0.f;
            op4[lane + i * 64] = o;
        }
    } else {
        // rare: keep x > T, then scatter Tf into the `needOut` lowest-index
        // ties (lowest-index-first matches lax.top_k stable ordering)
        #pragma unroll
        for (int i = 0; i < V4; ++i) {
            float4 o;
            o.x = (v[4*i+0] > T) ? __uint_as_float(v[4*i+0]) : 0.f;
            o.y = (v[4*i+1] > T) ? __uint_as_float(v[4*i+1]) : 0.f;
            o.z = (v[4*i+2] > T) ? __uint_as_float(v[4*i+2]) : 0.f;
            o.w = (v[4*i+3] > T) ? __uint_as_float(v[4*i+3]) : 0.f;
            op4[lane + i * 64] = o;
        }
        __asm__ volatile("s_waitcnt vmcnt(0)" ::: "memory"); // order fixups
        const float Tf = __uint_as_float(T);
        uint32_t last = 0u; bool first = true;
        for (uint32_t n = 0; n < needOut; ++n) {
            uint32_t mylow = 0xFFFFFFFFu;
            for (int i = lane; i < N; i += 64) {      // L2-hot re-scan
                float fv = rp[i];
                if (fv > 0.f && __float_as_uint(fv) == T) {
                    uint32_t col = (uint32_t)i;
                    if ((first || col > last) && col < mylow) mylow = col;
                }
            }
            uint32_t w = bf_min(mylow);
            if (w == 0xFFFFFFFFu) break;
            if (lane == 0) out[(size_t)row * N + w] = Tf;
            last = w; first = false;
        }
    }
}

extern "C" void kernel_launch(void* const* d_in, const int* in_sizes, int n_in,
                              void* d_out, int out_size, void* d_ws, size_t ws_size,
                              hipStream_t stream) {
    const float* A = (const float*)d_in[0];   // 8192*8192 fp32
    // d_in[1] (idx) is unused by the reference.
    float* out = (float*)d_out;
    topk_row_kernel<<<N / RPB, BLOCK, 0, stream>>>(A, out);
}